// Round 6
// baseline (151.040 us; speedup 1.0000x reference)
//
#include <hip/hip_runtime.h>
#include <stdint.h>

#define BHALF 4096
#define NROWS 8192
#define DDIM  512
#define KNEG  8190.0f

#define BM   128
#define BK   32
#define NK   (DDIM / BK)               // 16 K-steps
#define NTIL 64                        // 8192 / 128
#define TBLK (NTIL * (NTIL + 1) / 2)   // 2080 upper-triangle tiles
#define FABLK 256                      // finalize stage-A blocks (32 rows each)

typedef short v8s __attribute__((ext_vector_type(8)));   // 8 bf16 MFMA A/B frag
typedef float v4f __attribute__((ext_vector_type(4)));   // MFMA C/D frag

static __device__ inline float bf2f(uint32_t u) {
    union { uint32_t i; float f; } c; c.i = u << 16; return c.f;
}
static __device__ inline uint32_t f2bf(float f) {
    union { float f; uint32_t i; } c; c.f = f;
    return (c.i + 0x7fffu + ((c.i >> 16) & 1u)) >> 16;
}

// async global->LDS, 16 B per lane; LDS dest = wave-uniform base + lane*16
#define GLL16(gp, lp)                                                         \
    __builtin_amdgcn_global_load_lds(                                         \
        (__attribute__((address_space(1))) void*)(gp),                        \
        (__attribute__((address_space(3))) void*)(lp), 16, 0, 0)

// ---- frag-packed layout for cvt2 ----
// element (row, k) at byte offset (row>>4)*16384 + (k>>3)*256 + (row&15)*16 + (k&7)*2.
// One 16-row-group k-slab (BK=32) = 1 KiB contiguous -> one GLL16 per (rg, kb).
// An MFMA frag read from the LDS copy is contiguous lane*16 (conflict-free).

// -------- Kernel 1: per-row inverse L2 norm + bf16 frag-packed conversion ----
__global__ __launch_bounds__(256) void rownorm_cvt_kernel(
    const void* __restrict__ o1, const void* __restrict__ o2,
    float* __restrict__ rn, uint16_t* __restrict__ cvt2)
{
    int wave = threadIdx.x >> 6, lane = threadIdx.x & 63;
    int row = blockIdx.x * 4 + wave;

    // dtype probe: bits 7..14 = exponent of low bf16 (~127) vs fp32 mantissa noise
    uint32_t w = ((const uint32_t*)o1)[lane * 977 + 13];
    uint32_t e = (w >> 7) & 0xFFu;
    int bad = (e < 100u || e > 140u) ? 1 : 0;
    #pragma unroll
    for (int m = 32; m; m >>= 1) bad += __shfl_xor(bad, m);

    float ss;
    uint4 pack;                            // 8 bf16 = k in [8*lane, 8*lane+8)
    if (bad <= 16) {                       // bf16 inputs: copy-through
        const uint16_t* s = (row < BHALF)
            ? (const uint16_t*)o1 + (size_t)row * DDIM
            : (const uint16_t*)o2 + (size_t)(row - BHALF) * DDIM;
        pack = ((const uint4*)s)[lane];
        float a0 = bf2f(pack.x & 0xffffu), a1 = bf2f(pack.x >> 16);
        float a2 = bf2f(pack.y & 0xffffu), a3 = bf2f(pack.y >> 16);
        float a4 = bf2f(pack.z & 0xffffu), a5 = bf2f(pack.z >> 16);
        float a6 = bf2f(pack.w & 0xffffu), a7 = bf2f(pack.w >> 16);
        ss = a0*a0 + a1*a1 + a2*a2 + a3*a3 + a4*a4 + a5*a5 + a6*a6 + a7*a7;
    } else {                               // fp32 inputs: convert ONCE here
        const float* s = (row < BHALF)
            ? (const float*)o1 + (size_t)row * DDIM
            : (const float*)o2 + (size_t)(row - BHALF) * DDIM;
        float4 a = ((const float4*)s)[2 * lane];
        float4 b = ((const float4*)s)[2 * lane + 1];
        ss = a.x*a.x + a.y*a.y + a.z*a.z + a.w*a.w
           + b.x*b.x + b.y*b.y + b.z*b.z + b.w*b.w;
        pack.x = f2bf(a.x) | (f2bf(a.y) << 16);
        pack.y = f2bf(a.z) | (f2bf(a.w) << 16);
        pack.z = f2bf(b.x) | (f2bf(b.y) << 16);
        pack.w = f2bf(b.z) | (f2bf(b.w) << 16);
    }
    size_t byteoff = (size_t)(row >> 4) * 16384 + (size_t)lane * 256
                   + (size_t)(row & 15) * 16;
    *(uint4*)((char*)cvt2 + byteoff) = pack;

    #pragma unroll
    for (int m = 32; m; m >>= 1) ss += __shfl_xor(ss, m);
    if (lane == 0) rn[row] = rsqrtf(ss);
}

// -------- Kernel 2: Gram tiles, 2-buffer counted-vmcnt pipeline, 4 blk/CU ----
// Two barriers per K-step: start barrier (after vmcnt(4): this K-step's loads
// landed everywhere) and end barrier (all reads of buf[kb&1] retired, so the
// next iteration may overwrite it). GLL16(kb+1) issues before the start
// barrier, so its HBM/L2 latency hides under the previous step's MFMAs.
__global__ __launch_bounds__(256, 4) void SupCon_hcl_49323404427556_kernel(
    const uint16_t* __restrict__ cvt2, const float* __restrict__ rn,
    float* __restrict__ pden, float* __restrict__ pnum, float* __restrict__ cpos)
{
    __shared__ alignas(16) char sbuf[2][16384];   // 32 KiB: A half @0, B half @8192
    __shared__ float rnA[BM], rnB[BM];
    // reduction scratch aliases buf[0] (last read at kb=14, barrier-separated)
    float (*s_dr)[2] = (float(*)[2])(&sbuf[0][0]);
    float (*s_nr)[2] = (float(*)[2])(&sbuf[0][1024]);
    float (*s_dc)[2] = (float(*)[2])(&sbuf[0][2048]);
    float (*s_nc)[2] = (float(*)[2])(&sbuf[0][3072]);

    int tid  = threadIdx.x;
    int wave = tid >> 6, lane = tid & 63;
    int quad = lane >> 4, l16 = lane & 15;
    int wrow = (wave >> 1) * 64, wcol = (wave & 1) * 64;

    // ---- XCD-aware swizzle: 2080 = 8 * 260 exactly -> bijective ----
    int b = blockIdx.x;
    int t = (b & 7) * (TBLK / 8) + (b >> 3);

    // ---- triangular decode: t -> (bi, bj), bj >= bi ----
    int bi = (int)(64.5f - sqrtf(64.5f * 64.5f - 2.0f * (float)t));
    while (bi > 0 && (64 * bi - (bi * (bi - 1)) / 2) > t) --bi;
    while ((64 * (bi + 1) - ((bi + 1) * bi) / 2) <= t) ++bi;
    int bj = bi + (t - (64 * bi - (bi * (bi - 1)) / 2));
    int i0 = bi * BM, j0 = bj * BM;
    bool diag = (bi == bj);
    bool partner = (bj == bi + 32) && (bi < 32);
    bool plain = !diag && !partner;

    if (tid < BM) rnA[tid] = rn[i0 + tid];
    else          rnB[tid - BM] = rn[j0 + (tid - BM)];

    // ---- staging sources: wave w stages row-groups {2w, 2w+1} of A and B ----
    const char* cb = (const char*)cvt2;
    const char* gA0 = cb + ((size_t)(i0 >> 4) + 2 * wave) * 16384 + (size_t)lane * 16;
    const char* gA1 = gA0 + 16384;
    const char* gB0 = cb + ((size_t)(j0 >> 4) + 2 * wave) * 16384 + (size_t)lane * 16;
    const char* gB1 = gB0 + 16384;
    int dA0 = (2 * wave) * 1024, dA1 = dA0 + 1024;        // LDS dests (uniform)
    int dB0 = 8192 + dA0,        dB1 = dB0 + 1024;

    // prologue: stage kb=0 into buf 0 (diag stages B redundantly: uniform path)
    GLL16(gA0, &sbuf[0][dA0]);
    GLL16(gA1, &sbuf[0][dA1]);
    GLL16(gB0, &sbuf[0][dB0]);
    GLL16(gB1, &sbuf[0][dB1]);

    v4f acc[4][4];
    v4f z = {0.f, 0.f, 0.f, 0.f};
    #pragma unroll
    for (int a = 0; a < 4; ++a)
        #pragma unroll
        for (int bb = 0; bb < 4; ++bb) acc[a][bb] = z;

    int rgA = wrow >> 4, rgB = wcol >> 4;                  // 0 or 4

    #pragma unroll
    for (int kb = 0; kb < NK; ++kb) {
        if (kb < NK - 1) {
            char* wb = &sbuf[(kb + 1) & 1][0];
            GLL16(gA0 + (kb + 1) * 1024, wb + dA0);
            GLL16(gA1 + (kb + 1) * 1024, wb + dA1);
            GLL16(gB0 + (kb + 1) * 1024, wb + dB0);
            GLL16(gB1 + (kb + 1) * 1024, wb + dB1);
            asm volatile("s_waitcnt vmcnt(4)" ::: "memory");   // kb's loads done
        } else {
            asm volatile("s_waitcnt vmcnt(0)" ::: "memory");
        }
        __builtin_amdgcn_s_barrier();        // start: everyone's kb loads landed
        __builtin_amdgcn_sched_barrier(0);

        const char* rb = &sbuf[kb & 1][0];
        v8s af[4], bfr[4];
        #pragma unroll
        for (int tt = 0; tt < 4; ++tt) {
            af[tt]  = *(const v8s*)(rb + (rgA + tt) * 1024 + lane * 16);
            bfr[tt] = *(const v8s*)(rb + 8192 + (rgB + tt) * 1024 + lane * 16);
        }
        __builtin_amdgcn_s_setprio(1);
        #pragma unroll
        for (int mt = 0; mt < 4; ++mt)
            #pragma unroll
            for (int nt = 0; nt < 4; ++nt)
                acc[mt][nt] = __builtin_amdgcn_mfma_f32_16x16x32_bf16(
                    af[mt], bfr[nt], acc[mt][nt], 0, 0, 0);
        __builtin_amdgcn_s_setprio(0);
        __builtin_amdgcn_s_barrier();        // end: reads of buf[kb&1] retired
    }

    if (plain) {
        // ===== fast epilogue: one sweep, no masks, butterfly row-reduce =====
        float rjv[4];
        #pragma unroll
        for (int nt = 0; nt < 4; ++nt) rjv[nt] = rnB[wcol + 16 * nt + l16];

        float pd[16], pn[16], cdv[4], cnv[4];
        #pragma unroll
        for (int k = 0; k < 16; ++k) { pd[k] = 0.f; pn[k] = 0.f; }
        #pragma unroll
        for (int nt = 0; nt < 4; ++nt) { cdv[nt] = 0.f; cnv[nt] = 0.f; }

        #pragma unroll
        for (int mt = 0; mt < 4; ++mt) {
            #pragma unroll
            for (int r = 0; r < 4; ++r) {
                float ri = rnA[wrow + 16 * mt + quad * 4 + r];
                #pragma unroll
                for (int nt = 0; nt < 4; ++nt) {
                    float e  = __expf(acc[mt][nt][r] * ri * rjv[nt]);
                    float e3 = e * e * e;
                    pd[mt * 4 + r] += e;   pn[mt * 4 + r] += e3;
                    cdv[nt]        += e;   cnv[nt]        += e3;
                }
            }
        }

        #define BSTEP(arr, n, bit)                                            \
            _Pragma("unroll")                                                 \
            for (int p = 0; p < (n); ++p) {                                   \
                float mine = (l16 & (bit)) ? arr[2*p+1] : arr[2*p];           \
                float send = (l16 & (bit)) ? arr[2*p]   : arr[2*p+1];         \
                arr[p] = mine + __shfl_xor(send, (bit));                      \
            }
        BSTEP(pd, 8, 1) BSTEP(pd, 4, 2) BSTEP(pd, 2, 4) BSTEP(pd, 1, 8)
        BSTEP(pn, 8, 1) BSTEP(pn, 4, 2) BSTEP(pn, 2, 4) BSTEP(pn, 1, 8)
        #undef BSTEP

        int rowk = wrow + 16 * (l16 >> 2) + quad * 4 + (l16 & 3);
        s_dr[rowk][wcol >> 6] = pd[0];
        s_nr[rowk][wcol >> 6] = pn[0];

        #pragma unroll
        for (int nt = 0; nt < 4; ++nt) {
            float cd = cdv[nt] + __shfl_xor(cdv[nt], 16);
            cd += __shfl_xor(cd, 32);
            float cn = cnv[nt] + __shfl_xor(cnv[nt], 16);
            cn += __shfl_xor(cn, 32);
            if (quad == 0) {
                s_dc[wcol + 16 * nt + l16][wrow >> 6] = cd;
                s_nc[wcol + 16 * nt + l16][wrow >> 6] = cn;
            }
        }
    } else {
        // ===== general epilogue (diag + partner tiles, 96 of 2080) =====
        #pragma unroll
        for (int mt = 0; mt < 4; ++mt) {
            #pragma unroll
            for (int nt = 0; nt < 4; ++nt) {
                float rj = rnB[wcol + 16 * nt + l16];
                #pragma unroll
                for (int r = 0; r < 4; ++r) {
                    float ri = rnA[wrow + 16 * mt + quad * 4 + r];
                    acc[mt][nt][r] = __expf(acc[mt][nt][r] * ri * rj);
                }
            }
        }

        #pragma unroll
        for (int mt = 0; mt < 4; ++mt) {
            #pragma unroll
            for (int r = 0; r < 4; ++r) {
                int gil = wrow + 16 * mt + quad * 4 + r;
                int gi = i0 + gil;
                int pr = gi ^ BHALF;
                float pdv = 0.f, pnv = 0.f;
                #pragma unroll
                for (int nt = 0; nt < 4; ++nt) {
                    int gj = j0 + wcol + 16 * nt + l16;
                    float e = acc[mt][nt][r];
                    if (gj == pr) cpos[gi] = e * e;
                    if (gj != gi && gj != pr) { pdv += e; pnv += e * e * e; }
                }
                #pragma unroll
                for (int m = 1; m < 16; m <<= 1) {
                    pdv += __shfl_xor(pdv, m);
                    pnv += __shfl_xor(pnv, m);
                }
                if (l16 == 0) { s_dr[gil][wcol >> 6] = pdv; s_nr[gil][wcol >> 6] = pnv; }
            }
        }

        if (!diag) {
            #pragma unroll
            for (int nt = 0; nt < 4; ++nt) {
                int gjl = wcol + 16 * nt + l16;
                int gj = j0 + gjl;
                int pj = gj ^ BHALF;
                float cd = 0.f, cn = 0.f;
                #pragma unroll
                for (int mt = 0; mt < 4; ++mt) {
                    #pragma unroll
                    for (int r = 0; r < 4; ++r) {
                        int gi = i0 + wrow + 16 * mt + quad * 4 + r;
                        float e = acc[mt][nt][r];
                        if (gi == pj) cpos[gj] = e * e;
                        else { cd += e; cn += e * e * e; }
                    }
                }
                cd += __shfl_xor(cd, 16); cn += __shfl_xor(cn, 16);
                cd += __shfl_xor(cd, 32); cn += __shfl_xor(cn, 32);
                if (quad == 0) { s_dc[gjl][wrow >> 6] = cd; s_nc[gjl][wrow >> 6] = cn; }
            }
        }
    }

    __syncthreads();
    if (tid < BM) {
        pden[(size_t)bj * NROWS + i0 + tid] = s_dr[tid][0] + s_dr[tid][1];
        pnum[(size_t)bj * NROWS + i0 + tid] = s_nr[tid][0] + s_nr[tid][1];
        if (!diag) {
            pden[(size_t)bi * NROWS + j0 + tid] = s_dc[tid][0] + s_dc[tid][1];
            pnum[(size_t)bi * NROWS + j0 + tid] = s_nc[tid][0] + s_nc[tid][1];
        }
    }
}

// -------- Kernel 3a: fold 64 partials per row, 256 blocks (coalesced) --------
__global__ __launch_bounds__(256) void finalizeA_kernel(
    const float* __restrict__ pden, const float* __restrict__ pnum,
    const float* __restrict__ cpos, float* __restrict__ bpart)
{
    int b = blockIdx.x, t = threadIdx.x;
    int r = b * 32 + (t & 31);      // row
    int c = t >> 5;                 // chunk 0..7
    float pd = 0.f, pn = 0.f;
    #pragma unroll
    for (int i = 0; i < 8; ++i) {
        int x = c + 8 * i;
        pd += pden[(size_t)x * NROWS + r];
        pn += pnum[(size_t)x * NROWS + r];
    }
    pd += __shfl_xor(pd, 32);
    pn += __shfl_xor(pn, 32);

    __shared__ float sd[4][32], sn[4][32];
    int wave = t >> 6, lane = t & 63;
    if (lane < 32) { sd[wave][lane] = pd; sn[wave][lane] = pn; }
    __syncthreads();

    float s = 0.f;
    if (t < 32) {
        float d = sd[0][t] + sd[1][t] + sd[2][t] + sd[3][t];
        float n = sn[0][t] + sn[1][t] + sn[2][t] + sn[3][t];
        s = logf(1.0f + KNEG * (n / d) / cpos[b * 32 + t]);
    }
    if (t < 64) {
        #pragma unroll
        for (int m = 32; m; m >>= 1) s += __shfl_xor(s, m);
        if (t == 0) bpart[b] = s;
    }
}

// -------- Kernel 3b: final scalar over 256 block partials --------
__global__ __launch_bounds__(256) void finalizeB_kernel(
    const float* __restrict__ bpart, float* __restrict__ out)
{
    int t = threadIdx.x;
    float s = bpart[t];
    #pragma unroll
    for (int m = 32; m; m >>= 1) s += __shfl_xor(s, m);
    __shared__ float wsum[4];
    if ((t & 63) == 0) wsum[t >> 6] = s;
    __syncthreads();
    if (t == 0) out[0] = (wsum[0] + wsum[1] + wsum[2] + wsum[3]) / (float)NROWS;
}

extern "C" void kernel_launch(void* const* d_in, const int* in_sizes, int n_in,
                              void* d_out, int out_size, void* d_ws, size_t ws_size,
                              hipStream_t stream)
{
    const void* o1 = d_in[1];
    const void* o2 = d_in[2];

    // ws: cvt2 8MB | pden 2MB | pnum 2MB | rn 32KB | cpos 32KB | bpart 1KB
    uint16_t* cvt2 = (uint16_t*)d_ws;
    float* pden = (float*)(cvt2 + (size_t)NROWS * DDIM);
    float* pnum = pden + (size_t)NTIL * NROWS;
    float* rn   = pnum + (size_t)NTIL * NROWS;
    float* cpos = rn + NROWS;
    float* bpart= cpos + NROWS;

    rownorm_cvt_kernel<<<NROWS / 4, 256, 0, stream>>>(o1, o2, rn, cvt2);
    SupCon_hcl_49323404427556_kernel<<<TBLK, 256, 0, stream>>>(cvt2, rn, pden, pnum, cpos);
    finalizeA_kernel<<<FABLK, 256, 0, stream>>>(pden, pnum, cpos, bpart);
    finalizeB_kernel<<<1, 256, 0, stream>>>(bpart, (float*)d_out);
}

// Round 7
// 130.680 us; speedup vs baseline: 1.1558x; 1.1558x over previous
//
#include <hip/hip_runtime.h>
#include <stdint.h>

#define BHALF 4096
#define NROWS 8192
#define DDIM  512
#define KNEG  8190.0f

#define BM   128
#define BK   32
#define NK   (DDIM / BK)               // 16 K-steps
#define NTIL 64                        // 8192 / 128
#define TBLK (NTIL * (NTIL + 1) / 2)   // 2080 upper-triangle tiles
#define FABLK 256                      // finalize stage-A blocks (32 rows each)

typedef short v8s __attribute__((ext_vector_type(8)));   // 8 bf16 MFMA A/B frag
typedef float v4f __attribute__((ext_vector_type(4)));   // MFMA C/D frag

static __device__ inline float bf2f(uint32_t u) {
    union { uint32_t i; float f; } c; c.i = u << 16; return c.f;
}
static __device__ inline uint32_t f2bf(float f) {
    union { float f; uint32_t i; } c; c.f = f;
    return (c.i + 0x7fffu + ((c.i >> 16) & 1u)) >> 16;
}

// async global->LDS, 16 B per lane; LDS dest = wave-uniform base + lane*16
#define GLL16(gp, lp)                                                         \
    __builtin_amdgcn_global_load_lds(                                         \
        (__attribute__((address_space(1))) void*)(gp),                        \
        (__attribute__((address_space(3))) void*)(lp), 16, 0, 0)

// ---- frag-packed layout for cvt2 ----
// element (row, k) at byte offset (row>>4)*16384 + (k>>3)*256 + (row&15)*16 + (k&7)*2.
// One 16-row-group k-slab (BK=32) = 1 KiB contiguous -> one GLL16 per (rg, kb).
// An MFMA frag read from the LDS copy is contiguous lane*16 (conflict-free).

// -------- Kernel 1: per-row inverse L2 norm + bf16 frag-packed conversion ----
__global__ __launch_bounds__(256) void rownorm_cvt_kernel(
    const void* __restrict__ o1, const void* __restrict__ o2,
    float* __restrict__ rn, uint16_t* __restrict__ cvt2)
{
    int wave = threadIdx.x >> 6, lane = threadIdx.x & 63;
    int row = blockIdx.x * 4 + wave;

    // dtype probe: bits 7..14 = exponent of low bf16 (~127) vs fp32 mantissa noise
    uint32_t w = ((const uint32_t*)o1)[lane * 977 + 13];
    uint32_t e = (w >> 7) & 0xFFu;
    int bad = (e < 100u || e > 140u) ? 1 : 0;
    #pragma unroll
    for (int m = 32; m; m >>= 1) bad += __shfl_xor(bad, m);

    float ss;
    uint4 pack;                            // 8 bf16 = k in [8*lane, 8*lane+8)
    if (bad <= 16) {                       // bf16 inputs: copy-through
        const uint16_t* s = (row < BHALF)
            ? (const uint16_t*)o1 + (size_t)row * DDIM
            : (const uint16_t*)o2 + (size_t)(row - BHALF) * DDIM;
        pack = ((const uint4*)s)[lane];
        float a0 = bf2f(pack.x & 0xffffu), a1 = bf2f(pack.x >> 16);
        float a2 = bf2f(pack.y & 0xffffu), a3 = bf2f(pack.y >> 16);
        float a4 = bf2f(pack.z & 0xffffu), a5 = bf2f(pack.z >> 16);
        float a6 = bf2f(pack.w & 0xffffu), a7 = bf2f(pack.w >> 16);
        ss = a0*a0 + a1*a1 + a2*a2 + a3*a3 + a4*a4 + a5*a5 + a6*a6 + a7*a7;
    } else {                               // fp32 inputs: convert ONCE here
        const float* s = (row < BHALF)
            ? (const float*)o1 + (size_t)row * DDIM
            : (const float*)o2 + (size_t)(row - BHALF) * DDIM;
        float4 a = ((const float4*)s)[2 * lane];
        float4 b = ((const float4*)s)[2 * lane + 1];
        ss = a.x*a.x + a.y*a.y + a.z*a.z + a.w*a.w
           + b.x*b.x + b.y*b.y + b.z*b.z + b.w*b.w;
        pack.x = f2bf(a.x) | (f2bf(a.y) << 16);
        pack.y = f2bf(a.z) | (f2bf(a.w) << 16);
        pack.z = f2bf(b.x) | (f2bf(b.y) << 16);
        pack.w = f2bf(b.z) | (f2bf(b.w) << 16);
    }
    size_t byteoff = (size_t)(row >> 4) * 16384 + (size_t)lane * 256
                   + (size_t)(row & 15) * 16;
    *(uint4*)((char*)cvt2 + byteoff) = pack;

    #pragma unroll
    for (int m = 32; m; m >>= 1) ss += __shfl_xor(ss, m);
    if (lane == 0) rn[row] = rsqrtf(ss);
}

// -------- Kernel 2: Gram tiles, 3-buffer 2-deep counted-vmcnt pipeline ------
// Per K-step: { vmcnt(4) [kb's loads landed, kb+1's in flight] ; barrier ;
//   stage kb+2 -> buf[(kb+2)%3] ; ds_read buf[kb%3] ; MFMA }.
// Staging sits AFTER the barrier so each load gets ~2 iterations of latency
// cover (>= L2 latency). WAR safe: buf[(kb+2)%3]=buf[(kb-1)%3] reads retired
// before every wave reached barrier(kb). RAW safe: all waves ran their
// iter-kb vmcnt(4) before barrier(kb).
__global__ __launch_bounds__(256, 3) void SupCon_hcl_49323404427556_kernel(
    const uint16_t* __restrict__ cvt2, const float* __restrict__ rn,
    float* __restrict__ pden, float* __restrict__ pnum, float* __restrict__ cpos)
{
    __shared__ alignas(16) char sbuf[3][16384];   // 48 KiB: A half @0, B half @8192
    __shared__ float rnA[BM], rnB[BM];
    // reduction scratch aliases buf[1]: last GLL16 into buf[1] issued at kb=11
    // (drained by iter-13 vmcnt), last read at kb=13, two barriers before use.
    float (*s_dr)[2] = (float(*)[2])(&sbuf[1][0]);
    float (*s_nr)[2] = (float(*)[2])(&sbuf[1][1024]);
    float (*s_dc)[2] = (float(*)[2])(&sbuf[1][2048]);
    float (*s_nc)[2] = (float(*)[2])(&sbuf[1][3072]);

    int tid  = threadIdx.x;
    int wave = tid >> 6, lane = tid & 63;
    int quad = lane >> 4, l16 = lane & 15;
    int wrow = (wave >> 1) * 64, wcol = (wave & 1) * 64;

    // ---- XCD-aware swizzle: 2080 = 8 * 260 exactly -> bijective ----
    int b = blockIdx.x;
    int t = (b & 7) * (TBLK / 8) + (b >> 3);

    // ---- triangular decode: t -> (bi, bj), bj >= bi ----
    int bi = (int)(64.5f - sqrtf(64.5f * 64.5f - 2.0f * (float)t));
    while (bi > 0 && (64 * bi - (bi * (bi - 1)) / 2) > t) --bi;
    while ((64 * (bi + 1) - ((bi + 1) * bi) / 2) <= t) ++bi;
    int bj = bi + (t - (64 * bi - (bi * (bi - 1)) / 2));
    int i0 = bi * BM, j0 = bj * BM;
    bool diag = (bi == bj);
    bool partner = (bj == bi + 32) && (bi < 32);
    bool plain = !diag && !partner;

    if (tid < BM) rnA[tid] = rn[i0 + tid];
    else          rnB[tid - BM] = rn[j0 + (tid - BM)];

    // ---- staging sources: wave w stages row-groups {2w, 2w+1} of A and B ----
    const char* cb = (const char*)cvt2;
    const char* gA0 = cb + ((size_t)(i0 >> 4) + 2 * wave) * 16384 + (size_t)lane * 16;
    const char* gA1 = gA0 + 16384;
    const char* gB0 = cb + ((size_t)(j0 >> 4) + 2 * wave) * 16384 + (size_t)lane * 16;
    const char* gB1 = gB0 + 16384;
    int dA0 = (2 * wave) * 1024, dA1 = dA0 + 1024;        // LDS dests (uniform)
    int dB0 = 8192 + dA0,        dB1 = dB0 + 1024;

    // prologue: stage kb=0 -> buf0, kb=1 -> buf1 (diag stages B redundantly)
    GLL16(gA0, &sbuf[0][dA0]);
    GLL16(gA1, &sbuf[0][dA1]);
    GLL16(gB0, &sbuf[0][dB0]);
    GLL16(gB1, &sbuf[0][dB1]);
    GLL16(gA0 + 1024, &sbuf[1][dA0]);
    GLL16(gA1 + 1024, &sbuf[1][dA1]);
    GLL16(gB0 + 1024, &sbuf[1][dB0]);
    GLL16(gB1 + 1024, &sbuf[1][dB1]);

    v4f acc[4][4];
    v4f z = {0.f, 0.f, 0.f, 0.f};
    #pragma unroll
    for (int a = 0; a < 4; ++a)
        #pragma unroll
        for (int bb = 0; bb < 4; ++bb) acc[a][bb] = z;

    int rgA = wrow >> 4, rgB = wcol >> 4;                  // 0 or 4

    #pragma unroll
    for (int kb = 0; kb < NK; ++kb) {
        if (kb < NK - 1) {
            asm volatile("s_waitcnt vmcnt(4)" ::: "memory");   // kb's loads done
        } else {
            asm volatile("s_waitcnt vmcnt(0)" ::: "memory");
        }
        __builtin_amdgcn_s_barrier();        // everyone's kb loads landed
        __builtin_amdgcn_sched_barrier(0);

        if (kb < NK - 2) {                   // stage kb+2 (2-deep prefetch)
            char* wb = &sbuf[(kb + 2) % 3][0];
            GLL16(gA0 + (kb + 2) * 1024, wb + dA0);
            GLL16(gA1 + (kb + 2) * 1024, wb + dA1);
            GLL16(gB0 + (kb + 2) * 1024, wb + dB0);
            GLL16(gB1 + (kb + 2) * 1024, wb + dB1);
        }

        const char* rb = &sbuf[kb % 3][0];
        v8s af[4], bfr[4];
        #pragma unroll
        for (int tt = 0; tt < 4; ++tt) {
            af[tt]  = *(const v8s*)(rb + (rgA + tt) * 1024 + lane * 16);
            bfr[tt] = *(const v8s*)(rb + 8192 + (rgB + tt) * 1024 + lane * 16);
        }
        __builtin_amdgcn_s_setprio(1);
        #pragma unroll
        for (int mt = 0; mt < 4; ++mt)
            #pragma unroll
            for (int nt = 0; nt < 4; ++nt)
                acc[mt][nt] = __builtin_amdgcn_mfma_f32_16x16x32_bf16(
                    af[mt], bfr[nt], acc[mt][nt], 0, 0, 0);
        __builtin_amdgcn_s_setprio(0);
    }

    if (plain) {
        // ===== fast epilogue: one sweep, no masks, butterfly row-reduce =====
        float rjv[4];
        #pragma unroll
        for (int nt = 0; nt < 4; ++nt) rjv[nt] = rnB[wcol + 16 * nt + l16];

        float pd[16], pn[16], cdv[4], cnv[4];
        #pragma unroll
        for (int k = 0; k < 16; ++k) { pd[k] = 0.f; pn[k] = 0.f; }
        #pragma unroll
        for (int nt = 0; nt < 4; ++nt) { cdv[nt] = 0.f; cnv[nt] = 0.f; }

        #pragma unroll
        for (int mt = 0; mt < 4; ++mt) {
            #pragma unroll
            for (int r = 0; r < 4; ++r) {
                float ri = rnA[wrow + 16 * mt + quad * 4 + r];
                #pragma unroll
                for (int nt = 0; nt < 4; ++nt) {
                    float e  = __expf(acc[mt][nt][r] * ri * rjv[nt]);
                    float e3 = e * e * e;
                    pd[mt * 4 + r] += e;   pn[mt * 4 + r] += e3;
                    cdv[nt]        += e;   cnv[nt]        += e3;
                }
            }
        }

        #define BSTEP(arr, n, bit)                                            \
            _Pragma("unroll")                                                 \
            for (int p = 0; p < (n); ++p) {                                   \
                float mine = (l16 & (bit)) ? arr[2*p+1] : arr[2*p];           \
                float send = (l16 & (bit)) ? arr[2*p]   : arr[2*p+1];         \
                arr[p] = mine + __shfl_xor(send, (bit));                      \
            }
        BSTEP(pd, 8, 1) BSTEP(pd, 4, 2) BSTEP(pd, 2, 4) BSTEP(pd, 1, 8)
        BSTEP(pn, 8, 1) BSTEP(pn, 4, 2) BSTEP(pn, 2, 4) BSTEP(pn, 1, 8)
        #undef BSTEP

        int rowk = wrow + 16 * (l16 >> 2) + quad * 4 + (l16 & 3);
        s_dr[rowk][wcol >> 6] = pd[0];
        s_nr[rowk][wcol >> 6] = pn[0];

        #pragma unroll
        for (int nt = 0; nt < 4; ++nt) {
            float cd = cdv[nt] + __shfl_xor(cdv[nt], 16);
            cd += __shfl_xor(cd, 32);
            float cn = cnv[nt] + __shfl_xor(cnv[nt], 16);
            cn += __shfl_xor(cn, 32);
            if (quad == 0) {
                s_dc[wcol + 16 * nt + l16][wrow >> 6] = cd;
                s_nc[wcol + 16 * nt + l16][wrow >> 6] = cn;
            }
        }
    } else {
        // ===== general epilogue (diag + partner tiles, 96 of 2080) =====
        #pragma unroll
        for (int mt = 0; mt < 4; ++mt) {
            #pragma unroll
            for (int nt = 0; nt < 4; ++nt) {
                float rj = rnB[wcol + 16 * nt + l16];
                #pragma unroll
                for (int r = 0; r < 4; ++r) {
                    float ri = rnA[wrow + 16 * mt + quad * 4 + r];
                    acc[mt][nt][r] = __expf(acc[mt][nt][r] * ri * rj);
                }
            }
        }

        #pragma unroll
        for (int mt = 0; mt < 4; ++mt) {
            #pragma unroll
            for (int r = 0; r < 4; ++r) {
                int gil = wrow + 16 * mt + quad * 4 + r;
                int gi = i0 + gil;
                int pr = gi ^ BHALF;
                float pdv = 0.f, pnv = 0.f;
                #pragma unroll
                for (int nt = 0; nt < 4; ++nt) {
                    int gj = j0 + wcol + 16 * nt + l16;
                    float e = acc[mt][nt][r];
                    if (gj == pr) cpos[gi] = e * e;
                    if (gj != gi && gj != pr) { pdv += e; pnv += e * e * e; }
                }
                #pragma unroll
                for (int m = 1; m < 16; m <<= 1) {
                    pdv += __shfl_xor(pdv, m);
                    pnv += __shfl_xor(pnv, m);
                }
                if (l16 == 0) { s_dr[gil][wcol >> 6] = pdv; s_nr[gil][wcol >> 6] = pnv; }
            }
        }

        if (!diag) {
            #pragma unroll
            for (int nt = 0; nt < 4; ++nt) {
                int gjl = wcol + 16 * nt + l16;
                int gj = j0 + gjl;
                int pj = gj ^ BHALF;
                float cd = 0.f, cn = 0.f;
                #pragma unroll
                for (int mt = 0; mt < 4; ++mt) {
                    #pragma unroll
                    for (int r = 0; r < 4; ++r) {
                        int gi = i0 + wrow + 16 * mt + quad * 4 + r;
                        float e = acc[mt][nt][r];
                        if (gi == pj) cpos[gj] = e * e;
                        else { cd += e; cn += e * e * e; }
                    }
                }
                cd += __shfl_xor(cd, 16); cn += __shfl_xor(cn, 16);
                cd += __shfl_xor(cd, 32); cn += __shfl_xor(cn, 32);
                if (quad == 0) { s_dc[gjl][wrow >> 6] = cd; s_nc[gjl][wrow >> 6] = cn; }
            }
        }
    }

    __syncthreads();
    if (tid < BM) {
        pden[(size_t)bj * NROWS + i0 + tid] = s_dr[tid][0] + s_dr[tid][1];
        pnum[(size_t)bj * NROWS + i0 + tid] = s_nr[tid][0] + s_nr[tid][1];
        if (!diag) {
            pden[(size_t)bi * NROWS + j0 + tid] = s_dc[tid][0] + s_dc[tid][1];
            pnum[(size_t)bi * NROWS + j0 + tid] = s_nc[tid][0] + s_nc[tid][1];
        }
    }
}

// -------- Kernel 3a: fold 64 partials per row, 256 blocks (coalesced) --------
__global__ __launch_bounds__(256) void finalizeA_kernel(
    const float* __restrict__ pden, const float* __restrict__ pnum,
    const float* __restrict__ cpos, float* __restrict__ bpart)
{
    int b = blockIdx.x, t = threadIdx.x;
    int r = b * 32 + (t & 31);      // row
    int c = t >> 5;                 // chunk 0..7
    float pd = 0.f, pn = 0.f;
    #pragma unroll
    for (int i = 0; i < 8; ++i) {
        int x = c + 8 * i;
        pd += pden[(size_t)x * NROWS + r];
        pn += pnum[(size_t)x * NROWS + r];
    }
    pd += __shfl_xor(pd, 32);
    pn += __shfl_xor(pn, 32);

    __shared__ float sd[4][32], sn[4][32];
    int wave = t >> 6, lane = t & 63;
    if (lane < 32) { sd[wave][lane] = pd; sn[wave][lane] = pn; }
    __syncthreads();

    float s = 0.f;
    if (t < 32) {
        float d = sd[0][t] + sd[1][t] + sd[2][t] + sd[3][t];
        float n = sn[0][t] + sn[1][t] + sn[2][t] + sn[3][t];
        s = logf(1.0f + KNEG * (n / d) / cpos[b * 32 + t]);
    }
    if (t < 64) {
        #pragma unroll
        for (int m = 32; m; m >>= 1) s += __shfl_xor(s, m);
        if (t == 0) bpart[b] = s;
    }
}

// -------- Kernel 3b: final scalar over 256 block partials --------
__global__ __launch_bounds__(256) void finalizeB_kernel(
    const float* __restrict__ bpart, float* __restrict__ out)
{
    int t = threadIdx.x;
    float s = bpart[t];
    #pragma unroll
    for (int m = 32; m; m >>= 1) s += __shfl_xor(s, m);
    __shared__ float wsum[4];
    if ((t & 63) == 0) wsum[t >> 6] = s;
    __syncthreads();
    if (t == 0) out[0] = (wsum[0] + wsum[1] + wsum[2] + wsum[3]) / (float)NROWS;
}

extern "C" void kernel_launch(void* const* d_in, const int* in_sizes, int n_in,
                              void* d_out, int out_size, void* d_ws, size_t ws_size,
                              hipStream_t stream)
{
    const void* o1 = d_in[1];
    const void* o2 = d_in[2];

    // ws: cvt2 8MB | pden 2MB | pnum 2MB | rn 32KB | cpos 32KB | bpart 1KB
    uint16_t* cvt2 = (uint16_t*)d_ws;
    float* pden = (float*)(cvt2 + (size_t)NROWS * DDIM);
    float* pnum = pden + (size_t)NTIL * NROWS;
    float* rn   = pnum + (size_t)NTIL * NROWS;
    float* cpos = rn + NROWS;
    float* bpart= cpos + NROWS;

    rownorm_cvt_kernel<<<NROWS / 4, 256, 0, stream>>>(o1, o2, rn, cvt2);
    SupCon_hcl_49323404427556_kernel<<<TBLK, 256, 0, stream>>>(cvt2, rn, pden, pnum, cpos);
    finalizeA_kernel<<<FABLK, 256, 0, stream>>>(pden, pnum, cpos, bpart);
    finalizeB_kernel<<<1, 256, 0, stream>>>(bpart, (float*)d_out);
}